// Round 5
// baseline (231.045 us; speedup 1.0000x reference)
//
#include <hip/hip_runtime.h>
#include <hip/hip_bf16.h>

// LowRankBilinearFusion on MI355X (gfx950)
// Pipeline (3 dispatches):
//  1. convert: u,v,Wu,Wv fp32 -> bf16 into d_ws (memory-bound)
//  2. proj (merged): up_bf = u @ Wu^T ; vp_bf = v @ Wv^T   (bf16 MFMA GEMM,
//     global_load_lds staging, operand-swapped epilogue -> packed stores)
//  3. bilinear: per (b,m): o = relu( vp[b] @ (up[b,m] (.) Wp)^T + bp )
//     K-chunks of 64, vp via DMA into 2 unpadded half-buffers, W' = up(.)Wp
//     from fp32 Wp with perm-packing into padded LDS, operand-swapped MFMA
//     so the epilogue is float4 stores.

typedef __attribute__((ext_vector_type(8))) short short8;
typedef __attribute__((ext_vector_type(4))) float floatx4;
typedef __attribute__((ext_vector_type(4))) unsigned uintx4;

// Branch-free RNE fp32->bf16 (finite inputs).
__device__ __forceinline__ short f2bf(float f) {
    union { float f; unsigned u; } cv; cv.f = f;
    unsigned r = cv.u + 0x7fffu + ((cv.u >> 16) & 1u);
    return (short)(r >> 16);
}
__device__ __forceinline__ float bf2f(short s) {
    union { unsigned u; float f; } cv;
    cv.u = ((unsigned)(unsigned short)s) << 16; return cv.f;
}
// Pack hi16(a),hi16(b) -> dword (a in low short). Truncation (used for W').
__device__ __forceinline__ unsigned trunc2(float a, float b) {
    return __builtin_amdgcn_perm(__float_as_uint(b), __float_as_uint(a), 0x07060302);
}
// RNE-round two fp32 to bf16 pair packed in a dword (a low).
__device__ __forceinline__ unsigned rne2(float a, float b) {
    unsigned ua = __float_as_uint(a); ua += 0x7fffu + ((ua >> 16) & 1u);
    unsigned ub = __float_as_uint(b); ub += 0x7fffu + ((ub >> 16) & 1u);
    return __builtin_amdgcn_perm(ub, ua, 0x07060302);
}

#define GL2LDS(gptr, lptr) __builtin_amdgcn_global_load_lds(                    \
    (const __attribute__((address_space(1))) void*)(gptr),                      \
    (__attribute__((address_space(3))) void*)(lptr), 16, 0, 0)

// ---------------------------------------------------------------------------
#define N_U  1048576
#define N_V  8388608
#define N_WU 262144
#define N_WV 524288

__global__ __launch_bounds__(256) void convert_kernel(
    const float* __restrict__ u, const float* __restrict__ v,
    const float* __restrict__ Wu, const float* __restrict__ Wv,
    short* __restrict__ dst)
{
    const int n_u = N_U / 4, n_v = N_V / 4, n_wu = N_WU / 4, n_wv = N_WV / 4;
    const int total = n_u + n_v + n_wu + n_wv;
    for (int i4 = blockIdx.x * blockDim.x + threadIdx.x; i4 < total;
         i4 += gridDim.x * blockDim.x) {
        const float* src; int off = i4;
        if (off < n_u) src = u;
        else { off -= n_u;
            if (off < n_v) src = v;
            else { off -= n_v;
                if (off < n_wu) src = Wu;
                else { off -= n_wu; src = Wv; } } }
        float4 f = *((const float4*)src + off);
        uint2 o;
        o.x = rne2(f.x, f.y);
        o.y = rne2(f.z, f.w);
        *((uint2*)dst + i4) = o;
    }
}

// ---------------------------------------------------------------------------
// Merged projection GEMM (bf16 in/out): C[row][c] = sum_d X[row][d]*W[c][d]
// Blocks 0..63: u-proj (rows=1024, D=1024); 64..319: v-proj (rows=4096, D=2048)
// 64x64 tile, 256 threads (2x2 waves of 32x32), K-chunks of 32, DMA staging.
// mfma(W,X) operand order -> lane holds 4 consecutive c -> packed store.
// ---------------------------------------------------------------------------
__global__ __launch_bounds__(256) void proj_kernel(
    const short* __restrict__ Xu, const short* __restrict__ Wgu,
    short* __restrict__ Cu,
    const short* __restrict__ Xv, const short* __restrict__ Wgv,
    short* __restrict__ Cv)
{
    __shared__ short Xs[64 * 32];    // unpadded: required by global_load_lds
    __shared__ short Wsh[64 * 32];

    const int tid  = threadIdx.x;
    const int lane = tid & 63;
    const int wave = tid >> 6;
    const int quad = lane >> 4;
    const int l15  = lane & 15;

    int blk = blockIdx.x;
    const short *X, *W; short* C; int D;
    if (blk < 64) { X = Xu; W = Wgu; C = Cu; D = 1024; }
    else          { blk -= 64; X = Xv; W = Wgv; C = Cv; D = 2048; }
    const int r0 = (blk >> 2) * 64;
    const int c0 = (blk & 3) * 64;
    const int wr = (wave >> 1) * 32;
    const int wc = (wave & 1) * 32;

    const int sr  = tid >> 2;        // 0..63 staging row
    const int skg = (tid & 3) * 8;   // 0,8,16,24 shorts; LDS dst == tid*16 B

    floatx4 acc[2][2] = {};

    for (int kc = 0; kc < D; kc += 32) {
        __syncthreads();
        GL2LDS(X + (size_t)(r0 + sr) * D + kc + skg, &Xs[sr * 32 + skg]);
        GL2LDS(W + (size_t)(c0 + sr) * D + kc + skg, &Wsh[sr * 32 + skg]);
        __syncthreads();

        short8 a[2], bfr[2];
#pragma unroll
        for (int t = 0; t < 2; t++)
            a[t] = *(const short8*)&Xs[(wr + t * 16 + l15) * 32 + quad * 8];
#pragma unroll
        for (int t = 0; t < 2; t++)
            bfr[t] = *(const short8*)&Wsh[(wc + t * 16 + l15) * 32 + quad * 8];
        // swapped operands: D-row (quad*4+reg) = W-row (c), D-col (l15) = X-row
#pragma unroll
        for (int tn = 0; tn < 2; tn++)
#pragma unroll
            for (int tf = 0; tf < 2; tf++)
                acc[tn][tf] = __builtin_amdgcn_mfma_f32_16x16x32_bf16(
                    bfr[tf], a[tn], acc[tn][tf], 0, 0, 0);
    }

#pragma unroll
    for (int tn = 0; tn < 2; tn++)
#pragma unroll
        for (int tf = 0; tf < 2; tf++) {
            int xrow  = r0 + wr + tn * 16 + l15;
            int cbase = c0 + wc + tf * 16 + quad * 4;
            uint2 pk;
            pk.x = rne2(acc[tn][tf][0], acc[tn][tf][1]);
            pk.y = rne2(acc[tn][tf][2], acc[tn][tf][3]);
            *(uint2*)&C[(size_t)xrow * 256 + cbase] = pk;
        }
}

// ---------------------------------------------------------------------------
// Bilinear fusion. One block = one (b,m) x one 128-wide f-half.
// n=128 x f=128 tile, 4 waves 2x2, each wave 64x64 (4x4 MFMA tiles).
// K=256 in chunks of 64 (two 32-k MFMA steps per staged chunk).
// vp: DMA into two unpadded stride-32 half-buffers. W' = up(.)Wp from fp32 Wp,
// perm-truncated, stride-72 padded LDS. mfma(W',vp) -> float4 epilogue.
// ---------------------------------------------------------------------------
__global__ __launch_bounds__(256) void bilinear_kernel(
    const short* __restrict__ up, const short* __restrict__ vp,
    const float* __restrict__ Wp, const float* __restrict__ bp,
    float* __restrict__ out)
{
    __shared__ short vp_s[2][128 * 32];  // two k-halves, unpadded (DMA)
    __shared__ short Ws[128 * 72];       // stride 72 shorts = 144 B (bank rot 4)
    __shared__ float up_s[256];

    const int tid  = threadIdx.x;
    const int lane = tid & 63;
    const int wave = tid >> 6;
    const int quad = lane >> 4;
    const int l15  = lane & 15;

    const int f_blk = blockIdx.x & 1;
    const int bm    = blockIdx.x >> 1;   // b*32 + m
    const int b     = bm >> 5;
    const int f0    = f_blk * 128;
    const int wn    = (wave >> 1) * 64;
    const int wf    = (wave & 1) * 64;

    up_s[tid] = bf2f(up[(size_t)bm * 256 + tid]);

    const int sr   = tid >> 2;          // 0..63   (vp DMA row)
    const int skg  = (tid & 3) * 8;     // 0,8,16,24 shorts
    const int wrow = tid >> 1;          // 0..127  (W' staging row)
    const int kh   = (tid & 1) * 32;    // 0 or 32 shorts

    floatx4 acc[4][4] = {};

    for (int kc = 0; kc < 256; kc += 64) {
        __syncthreads();   // also publishes up_s on first iteration
        {   // vp slice 128 x 64 via DMA: 4 issues/thread into 2 half-buffers
            const short* g = vp + (size_t)(b * 128 + sr) * 256 + kc + skg;
            GL2LDS(g,                 &vp_s[0][sr * 32 + skg]);
            GL2LDS(g + 64 * 256,      &vp_s[0][(64 + sr) * 32 + skg]);
            GL2LDS(g + 32,            &vp_s[1][sr * 32 + skg]);
            GL2LDS(g + 64 * 256 + 32, &vp_s[1][(64 + sr) * 32 + skg]);
        }
        {   // W' slice: 128 x 64 = trunc_bf16( Wp_f32 * up[k] ), 32 elems/thread
            const float* wpr = Wp + (size_t)(f0 + wrow) * 256 + kc + kh;
            const float* usr = &up_s[kc + kh];
#pragma unroll
            for (int h = 0; h < 4; h++) {
                float w[8], uu[8];
                *(float4*)&w[0]  = *(const float4*)(wpr + 8 * h);
                *(float4*)&w[4]  = *(const float4*)(wpr + 8 * h + 4);
                *(float4*)&uu[0] = *(const float4*)(usr + 8 * h);
                *(float4*)&uu[4] = *(const float4*)(usr + 8 * h + 4);
                uintx4 o;
#pragma unroll
                for (int i = 0; i < 4; i++)
                    o[i] = trunc2(w[2 * i] * uu[2 * i], w[2 * i + 1] * uu[2 * i + 1]);
                *(uintx4*)&Ws[wrow * 72 + kh + 8 * h] = o;
            }
        }
        __syncthreads();

#pragma unroll
        for (int kk2 = 0; kk2 < 2; kk2++) {
            short8 a[4], bfr[4];
#pragma unroll
            for (int t = 0; t < 4; t++)
                a[t] = *(const short8*)&vp_s[kk2][(wn + t * 16 + l15) * 32 + quad * 8];
#pragma unroll
            for (int t = 0; t < 4; t++)
                bfr[t] = *(const short8*)&Ws[(wf + t * 16 + l15) * 72 + kk2 * 32 + quad * 8];
            // swapped: D-row (quad*4+reg) = f, D-col (l15) = n
#pragma unroll
            for (int tn = 0; tn < 4; tn++)
#pragma unroll
                for (int tf = 0; tf < 4; tf++)
                    acc[tn][tf] = __builtin_amdgcn_mfma_f32_16x16x32_bf16(
                        bfr[tf], a[tn], acc[tn][tf], 0, 0, 0);
        }
    }

    float4 bpv[4];
#pragma unroll
    for (int tf = 0; tf < 4; tf++)
        bpv[tf] = *(const float4*)&bp[f0 + wf + tf * 16 + quad * 4];

    const size_t out_base = (size_t)bm * 128 * 256;
#pragma unroll
    for (int tn = 0; tn < 4; tn++) {
        const int n = wn + tn * 16 + l15;
        float* orow = out + out_base + (size_t)n * 256;
#pragma unroll
        for (int tf = 0; tf < 4; tf++) {
            const int fbase = f0 + wf + tf * 16 + quad * 4;
            float4 o;
            o.x = fmaxf(acc[tn][tf][0] + bpv[tf].x, 0.0f);
            o.y = fmaxf(acc[tn][tf][1] + bpv[tf].y, 0.0f);
            o.z = fmaxf(acc[tn][tf][2] + bpv[tf].z, 0.0f);
            o.w = fmaxf(acc[tn][tf][3] + bpv[tf].w, 0.0f);
            *(float4*)(orow + fbase) = o;
        }
    }
}

extern "C" void kernel_launch(void* const* d_in, const int* in_sizes, int n_in,
                              void* d_out, int out_size, void* d_ws, size_t ws_size,
                              hipStream_t stream) {
    const float* u  = (const float*)d_in[0];   // (32,32,1024)
    const float* v  = (const float*)d_in[1];   // (32,128,2048)
    const float* Wu = (const float*)d_in[2];   // (256,1024)
    const float* Wv = (const float*)d_in[3];   // (256,2048)
    const float* Wp = (const float*)d_in[4];   // (256,256) fp32, used directly
    const float* bp = (const float*)d_in[5];   // (256,)
    float* out = (float*)d_out;                // (32,32,128,256)

    short* bf    = (short*)d_ws;
    short* u_bf  = bf;                 // 1,048,576
    short* v_bf  = u_bf + N_U;         // 8,388,608
    short* Wu_bf = v_bf + N_V;         // 262,144
    short* Wv_bf = Wu_bf + N_WU;       // 524,288
    short* up_bf = Wv_bf + N_WV;       // 1024x256
    short* vp_bf = up_bf + 262144;     // 4096x256

    convert_kernel<<<dim3(2048), dim3(256), 0, stream>>>(u, v, Wu, Wv, bf);
    // blocks 0..63: up (16 rblk x 4 cblk); 64..319: vp (64 rblk x 4 cblk)
    proj_kernel<<<dim3(320), dim3(256), 0, stream>>>(
        u_bf, Wu_bf, up_bf, v_bf, Wv_bf, vp_bf);
    bilinear_kernel<<<dim3(2048), dim3(256), 0, stream>>>(
        up_bf, vp_bf, Wp, bp, out);
}

// Round 6
// 219.406 us; speedup vs baseline: 1.0530x; 1.0530x over previous
//
#include <hip/hip_runtime.h>
#include <hip/hip_bf16.h>

// LowRankBilinearFusion on MI355X (gfx950)
// Pipeline (3 dispatches):
//  1. convert: u,v,Wu,Wv fp32 -> bf16 into d_ws (memory-bound)
//  2. proj (merged): up_bf = u @ Wu^T ; vp_bf = v @ Wv^T   (bf16 MFMA GEMM,
//     K-chunk 128 via 4x 64B-row DMA sub-buffers; grid-limited so LDS free)
//  3. bilinear: per (b,m): o = relu( vp[b] @ (up[b,m] (.) Wp)^T + bp )
//     K=32 chunks (18 KB LDS), vp via DMA (unpadded 64B rows), W' = up(.)Wp
//     from fp32 Wp (loads issued before DMAs), trunc+perm pack into stride-36
//     LDS; operand-swapped MFMA -> float4 epilogue.

typedef __attribute__((ext_vector_type(8))) short short8;
typedef __attribute__((ext_vector_type(4))) float floatx4;
typedef __attribute__((ext_vector_type(4))) unsigned uintx4;

__device__ __forceinline__ float bf2f(short s) {
    union { unsigned u; float f; } cv;
    cv.u = ((unsigned)(unsigned short)s) << 16; return cv.f;
}
// Pack hi16(a),hi16(b) -> dword (a in low short). Truncation (used for W').
__device__ __forceinline__ unsigned trunc2(float a, float b) {
    return __builtin_amdgcn_perm(__float_as_uint(b), __float_as_uint(a), 0x07060302);
}
// RNE-round two fp32 to bf16 pair packed in a dword (a low).
__device__ __forceinline__ unsigned rne2(float a, float b) {
    unsigned ua = __float_as_uint(a); ua += 0x7fffu + ((ua >> 16) & 1u);
    unsigned ub = __float_as_uint(b); ub += 0x7fffu + ((ub >> 16) & 1u);
    return __builtin_amdgcn_perm(ub, ua, 0x07060302);
}

#define GL2LDS(gptr, lptr) __builtin_amdgcn_global_load_lds(                    \
    (const __attribute__((address_space(1))) void*)(gptr),                      \
    (__attribute__((address_space(3))) void*)(lptr), 16, 0, 0)

// ---------------------------------------------------------------------------
#define N_U  1048576
#define N_V  8388608
#define N_WU 262144
#define N_WV 524288

__global__ __launch_bounds__(256) void convert_kernel(
    const float* __restrict__ u, const float* __restrict__ v,
    const float* __restrict__ Wu, const float* __restrict__ Wv,
    short* __restrict__ dst)
{
    const int n_u = N_U / 4, n_v = N_V / 4, n_wu = N_WU / 4, n_wv = N_WV / 4;
    const int total = n_u + n_v + n_wu + n_wv;
    for (int i4 = blockIdx.x * blockDim.x + threadIdx.x; i4 < total;
         i4 += gridDim.x * blockDim.x) {
        const float* src; int off = i4;
        if (off < n_u) src = u;
        else { off -= n_u;
            if (off < n_v) src = v;
            else { off -= n_v;
                if (off < n_wu) src = Wu;
                else { off -= n_wu; src = Wv; } } }
        float4 f = *((const float4*)src + off);
        uint2 o;
        o.x = rne2(f.x, f.y);
        o.y = rne2(f.z, f.w);
        *((uint2*)dst + i4) = o;
    }
}

// ---------------------------------------------------------------------------
// Merged projection GEMM (bf16 in/out): C[row][c] = sum_d X[row][d]*W[c][d]
// Blocks 0..63: u-proj (rows=1024, D=1024); 64..319: v-proj (rows=4096, D=2048)
// 64x64 tile, 256 threads (2x2 waves of 32x32). K-chunks of 128 staged as
// 4 sub-buffers with 64 B rows (DMA-legal + conflict-floor banking).
// mfma(W,X) operand order -> lane holds 4 consecutive c -> packed store.
// ---------------------------------------------------------------------------
__global__ __launch_bounds__(256) void proj_kernel(
    const short* __restrict__ Xu, const short* __restrict__ Wgu,
    short* __restrict__ Cu,
    const short* __restrict__ Xv, const short* __restrict__ Wgv,
    short* __restrict__ Cv)
{
    __shared__ short Xs[4][64 * 32];    // 4 k-sub-chunks of 32, 64 B rows
    __shared__ short Wsh[4][64 * 32];

    const int tid  = threadIdx.x;
    const int lane = tid & 63;
    const int wave = tid >> 6;
    const int quad = lane >> 4;
    const int l15  = lane & 15;

    int blk = blockIdx.x;
    const short *X, *W; short* C; int D;
    if (blk < 64) { X = Xu; W = Wgu; C = Cu; D = 1024; }
    else          { blk -= 64; X = Xv; W = Wgv; C = Cv; D = 2048; }
    const int r0 = (blk >> 2) * 64;
    const int c0 = (blk & 3) * 64;
    const int wr = (wave >> 1) * 32;
    const int wc = (wave & 1) * 32;

    const int sr  = tid >> 2;        // 0..63 staging row
    const int skg = (tid & 3) * 8;   // 0,8,16,24 shorts; LDS dst == tid*16 B

    floatx4 acc[2][2] = {};

    for (int kc = 0; kc < D; kc += 128) {
        __syncthreads();
        const size_t xoff = (size_t)(r0 + sr) * D + kc + skg;
        const size_t woff = (size_t)(c0 + sr) * D + kc + skg;
#pragma unroll
        for (int s = 0; s < 4; s++) {
            GL2LDS(X + xoff + s * 32, &Xs[s][sr * 32 + skg]);
            GL2LDS(W + woff + s * 32, &Wsh[s][sr * 32 + skg]);
        }
        __syncthreads();

#pragma unroll
        for (int s = 0; s < 4; s++) {
            short8 a[2], bfr[2];
#pragma unroll
            for (int t = 0; t < 2; t++)
                a[t] = *(const short8*)&Xs[s][(wr + t * 16 + l15) * 32 + quad * 8];
#pragma unroll
            for (int t = 0; t < 2; t++)
                bfr[t] = *(const short8*)&Wsh[s][(wc + t * 16 + l15) * 32 + quad * 8];
            // swapped: D-row (quad*4+reg) = W-row (c), D-col (l15) = X-row
#pragma unroll
            for (int tn = 0; tn < 2; tn++)
#pragma unroll
                for (int tf = 0; tf < 2; tf++)
                    acc[tn][tf] = __builtin_amdgcn_mfma_f32_16x16x32_bf16(
                        bfr[tf], a[tn], acc[tn][tf], 0, 0, 0);
        }
    }

#pragma unroll
    for (int tn = 0; tn < 2; tn++)
#pragma unroll
        for (int tf = 0; tf < 2; tf++) {
            int xrow  = r0 + wr + tn * 16 + l15;
            int cbase = c0 + wc + tf * 16 + quad * 4;
            uint2 pk;
            pk.x = rne2(acc[tn][tf][0], acc[tn][tf][1]);
            pk.y = rne2(acc[tn][tf][2], acc[tn][tf][3]);
            *(uint2*)&C[(size_t)xrow * 256 + cbase] = pk;
        }
}

// ---------------------------------------------------------------------------
// Bilinear fusion. One block = one (b,m) x one 128-wide f-half.
// n=128 x f=128 tile, 4 waves 2x2, each wave 64x64 (4x4 MFMA tiles).
// K=256 in chunks of 32. vp: DMA, unpadded 64 B rows. W' = up(.)Wp from fp32
// Wp (issued before DMA), perm-truncated into stride-36 LDS (conflict-free
// reads, 2-way-free writes). mfma(W',vp) -> float4 epilogue.
// ---------------------------------------------------------------------------
__global__ __launch_bounds__(256) void bilinear_kernel(
    const short* __restrict__ up, const short* __restrict__ vp,
    const float* __restrict__ Wp, const float* __restrict__ bp,
    float* __restrict__ out)
{
    __shared__ short vp_s[128 * 32];   // unpadded (DMA), 64 B rows
    __shared__ short Ws[128 * 36];     // stride 36 shorts = 72 B
    __shared__ float up_s[256];

    const int tid  = threadIdx.x;
    const int lane = tid & 63;
    const int wave = tid >> 6;
    const int quad = lane >> 4;
    const int l15  = lane & 15;

    const int f_blk = blockIdx.x & 1;
    const int bm    = blockIdx.x >> 1;   // b*32 + m
    const int b     = bm >> 5;
    const int f0    = f_blk * 128;
    const int wn    = (wave >> 1) * 64;
    const int wf    = (wave & 1) * 64;

    up_s[tid] = bf2f(up[(size_t)bm * 256 + tid]);

    const int sr  = tid >> 2;          // 0..63   (vp DMA row)
    const int skg = (tid & 3) * 8;     // 0,8,16,24 shorts
    const int sn  = tid >> 1;          // 0..127  (W' staging row)
    const int skh = (tid & 1) * 16;    // 0 or 16 shorts

    floatx4 acc[4][4] = {};

    for (int kc = 0; kc < 256; kc += 32) {
        __syncthreads();   // also publishes up_s on first iteration
        // 1) Wp fp32 loads first (oldest in vmcnt queue -> W' compute does
        //    not wait on the DMAs below)
        const float* wpr = Wp + (size_t)(f0 + sn) * 256 + kc + skh;
        float w[16];
        *(float4*)&w[0]  = *(const float4*)(wpr);
        *(float4*)&w[4]  = *(const float4*)(wpr + 4);
        *(float4*)&w[8]  = *(const float4*)(wpr + 8);
        *(float4*)&w[12] = *(const float4*)(wpr + 12);
        // 2) vp slice 128 x 32 via DMA (8 KB)
        {
            const short* g = vp + (size_t)(b * 128 + sr) * 256 + kc + skg;
            GL2LDS(g,            &vp_s[sr * 32 + skg]);
            GL2LDS(g + 64 * 256, &vp_s[(64 + sr) * 32 + skg]);
        }
        // 3) W' = trunc_bf16( Wp * up[k] ), 16 elems/thread
        {
            const float* usr = &up_s[kc + skh];
            float uu[16];
            *(float4*)&uu[0]  = *(const float4*)(usr);
            *(float4*)&uu[4]  = *(const float4*)(usr + 4);
            *(float4*)&uu[8]  = *(const float4*)(usr + 8);
            *(float4*)&uu[12] = *(const float4*)(usr + 12);
            uintx4 o0, o1;
#pragma unroll
            for (int i = 0; i < 4; i++)
                o0[i] = trunc2(w[2 * i] * uu[2 * i], w[2 * i + 1] * uu[2 * i + 1]);
#pragma unroll
            for (int i = 0; i < 4; i++)
                o1[i] = trunc2(w[8 + 2 * i] * uu[8 + 2 * i], w[9 + 2 * i] * uu[9 + 2 * i]);
            *(uintx4*)&Ws[sn * 36 + skh]     = o0;
            *(uintx4*)&Ws[sn * 36 + skh + 8] = o1;
        }
        __syncthreads();

        short8 a[4], bfr[4];
#pragma unroll
        for (int t = 0; t < 4; t++)
            a[t] = *(const short8*)&vp_s[(wn + t * 16 + l15) * 32 + quad * 8];
#pragma unroll
        for (int t = 0; t < 4; t++)
            bfr[t] = *(const short8*)&Ws[(wf + t * 16 + l15) * 36 + quad * 8];
        // swapped: D-row (quad*4+reg) = f, D-col (l15) = n
#pragma unroll
        for (int tn = 0; tn < 4; tn++)
#pragma unroll
            for (int tf = 0; tf < 4; tf++)
                acc[tn][tf] = __builtin_amdgcn_mfma_f32_16x16x32_bf16(
                    bfr[tf], a[tn], acc[tn][tf], 0, 0, 0);
    }

    float4 bpv[4];
#pragma unroll
    for (int tf = 0; tf < 4; tf++)
        bpv[tf] = *(const float4*)&bp[f0 + wf + tf * 16 + quad * 4];

    const size_t out_base = (size_t)bm * 128 * 256;
#pragma unroll
    for (int tn = 0; tn < 4; tn++) {
        const int n = wn + tn * 16 + l15;
        float* orow = out + out_base + (size_t)n * 256;
#pragma unroll
        for (int tf = 0; tf < 4; tf++) {
            const int fbase = f0 + wf + tf * 16 + quad * 4;
            float4 o;
            o.x = fmaxf(acc[tn][tf][0] + bpv[tf].x, 0.0f);
            o.y = fmaxf(acc[tn][tf][1] + bpv[tf].y, 0.0f);
            o.z = fmaxf(acc[tn][tf][2] + bpv[tf].z, 0.0f);
            o.w = fmaxf(acc[tn][tf][3] + bpv[tf].w, 0.0f);
            *(float4*)(orow + fbase) = o;
        }
    }
}

extern "C" void kernel_launch(void* const* d_in, const int* in_sizes, int n_in,
                              void* d_out, int out_size, void* d_ws, size_t ws_size,
                              hipStream_t stream) {
    const float* u  = (const float*)d_in[0];   // (32,32,1024)
    const float* v  = (const float*)d_in[1];   // (32,128,2048)
    const float* Wu = (const float*)d_in[2];   // (256,1024)
    const float* Wv = (const float*)d_in[3];   // (256,2048)
    const float* Wp = (const float*)d_in[4];   // (256,256) fp32, used directly
    const float* bp = (const float*)d_in[5];   // (256,)
    float* out = (float*)d_out;                // (32,32,128,256)

    short* bf    = (short*)d_ws;
    short* u_bf  = bf;                 // 1,048,576
    short* v_bf  = u_bf + N_U;         // 8,388,608
    short* Wu_bf = v_bf + N_V;         // 262,144
    short* Wv_bf = Wu_bf + N_WU;       // 524,288
    short* up_bf = Wv_bf + N_WV;       // 1024x256
    short* vp_bf = up_bf + 262144;     // 4096x256

    convert_kernel<<<dim3(2048), dim3(256), 0, stream>>>(u, v, Wu, Wv, bf);
    // blocks 0..63: up (16 rblk x 4 cblk); 64..319: vp (64 rblk x 4 cblk)
    proj_kernel<<<dim3(320), dim3(256), 0, stream>>>(
        u_bf, Wu_bf, up_bf, v_bf, Wv_bf, vp_bf);
    bilinear_kernel<<<dim3(2048), dim3(256), 0, stream>>>(
        up_bf, vp_bf, Wp, bp, out);
}